// Round 5
// baseline (355.247 us; speedup 1.0000x reference)
//
#include <hip/hip_runtime.h>
#include <math.h>

#define FDIM 128
#define NP 32                 // CSR partition blocks
#define NMAX 10240            // LDS histogram capacity (N=10000)
static constexpr float SC2 = 0.17677669529663687f * 1.4426950408889634f; // (1/sqrt(32))*log2(e)
static constexpr float LN_EPS = 1e-5f;

__device__ __forceinline__ unsigned short f2bf(float f) {
    unsigned u = __float_as_uint(f);
    unsigned r = u + 0x7FFFu + ((u >> 16) & 1u);   // RNE
    return (unsigned short)(r >> 16);
}

// ---------------------------------------------------------------------------
// K1: per-block LDS histogram of dst -> bh[p*N+d] (coalesced). No global atomics.
// ---------------------------------------------------------------------------
__global__ __launch_bounds__(256) void hist_kernel(
    const int* __restrict__ dst, int* __restrict__ bh, int N, int E, int C)
{
    __shared__ int h[NMAX];
    const int p = blockIdx.x, tid = threadIdx.x;
    for (int i = tid; i < N; i += 256) h[i] = 0;
    __syncthreads();

    const int lo = p * C;
    const int hi = min(lo + C, E);
    const int n = hi - lo;
    if (n > 0) {
        if ((E & 3) == 0) {            // C mult of 4 -> lo mult of 4
            const int4* d4 = (const int4*)(dst + lo);
            const int n4 = n >> 2;
            for (int i = tid; i < n4; i += 256) {
                int4 d = d4[i];
                atomicAdd(&h[d.x], 1); atomicAdd(&h[d.y], 1);
                atomicAdd(&h[d.z], 1); atomicAdd(&h[d.w], 1);
            }
            for (int i = lo + (n4 << 2) + tid; i < hi; i += 256)
                atomicAdd(&h[dst[i]], 1);
        } else {
            for (int i = lo + tid; i < hi; i += 256)
                atomicAdd(&h[dst[i]], 1);
        }
    }
    __syncthreads();
    for (int i = tid; i < N; i += 256) bh[p * N + i] = h[i];
}

// ---------------------------------------------------------------------------
// K2: pure 4-way GEMM. grid (ceil(N/64), 4), block 256.
// Q, R fp32; K, V bf16 interleaved KVu[n][256] (K@0, V@128).
// ---------------------------------------------------------------------------
__global__ __launch_bounds__(256) void gemm_kernel(
    const float* __restrict__ nodes,
    const float* __restrict__ Wq, const float* __restrict__ Wk,
    const float* __restrict__ Wv, const float* __restrict__ Wr,
    const float* __restrict__ br,
    float* __restrict__ Qb, unsigned short* __restrict__ KVu,
    float* __restrict__ Rb, int N)
{
    __shared__ float As[64][FDIM];
    const int row0 = blockIdx.x * 64;
    const int wi = blockIdx.y;
    const float* __restrict__ W = (wi == 0) ? Wq : (wi == 1) ? Wk : (wi == 2) ? Wv : Wr;
    const int tid = threadIdx.x;

    // stage A tile with float4 (8 per thread)
    #pragma unroll
    for (int i = 0; i < 8; ++i) {
        int idx = tid + i * 256;          // 0..2047 float4s
        int r = idx >> 5, c4 = idx & 31;
        int gr = row0 + r;
        float4 v = make_float4(0.f, 0.f, 0.f, 0.f);
        if (gr < N) v = *reinterpret_cast<const float4*>(&nodes[(size_t)gr * FDIM + c4 * 4]);
        *reinterpret_cast<float4*>(&As[r][c4 * 4]) = v;
    }
    __syncthreads();

    const int cg = tid & 31;
    const int rg = tid >> 5;
    const int c0 = cg * 4;
    const int r0 = rg * 8;

    float acc[8][4];
    #pragma unroll
    for (int i = 0; i < 8; ++i)
        #pragma unroll
        for (int j = 0; j < 4; ++j) acc[i][j] = 0.f;

    #pragma unroll 2
    for (int k = 0; k < FDIM; k += 2) {
        const float4 wA = *reinterpret_cast<const float4*>(&W[k * FDIM + c0]);
        const float4 wB = *reinterpret_cast<const float4*>(&W[(k + 1) * FDIM + c0]);
        float2 a[8];
        #pragma unroll
        for (int i = 0; i < 8; ++i)
            a[i] = *reinterpret_cast<const float2*>(&As[r0 + i][k]);
        #pragma unroll
        for (int i = 0; i < 8; ++i) {
            acc[i][0] += a[i].x * wA.x + a[i].y * wB.x;
            acc[i][1] += a[i].x * wA.y + a[i].y * wB.y;
            acc[i][2] += a[i].x * wA.z + a[i].y * wB.z;
            acc[i][3] += a[i].x * wA.w + a[i].y * wB.w;
        }
    }

    float4 bias = make_float4(0.f, 0.f, 0.f, 0.f);
    if (wi == 3) bias = *reinterpret_cast<const float4*>(&br[c0]);

    #pragma unroll
    for (int i = 0; i < 8; ++i) {
        int gr = row0 + r0 + i;
        if (gr >= N) continue;
        if (wi == 0 || wi == 3) {
            float4 o = make_float4(acc[i][0] + bias.x, acc[i][1] + bias.y,
                                   acc[i][2] + bias.z, acc[i][3] + bias.w);
            float* dp = (wi == 0) ? &Qb[(size_t)gr * 128 + c0] : &Rb[(size_t)gr * 128 + c0];
            *reinterpret_cast<float4*>(dp) = o;
        } else {
            ushort4 o;
            o.x = f2bf(acc[i][0]); o.y = f2bf(acc[i][1]);
            o.z = f2bf(acc[i][2]); o.w = f2bf(acc[i][3]);
            unsigned short* dp = &KVu[(size_t)gr * 256 + ((wi == 2) ? 128 : 0) + c0];
            *reinterpret_cast<ushort4*>(dp) = o;
        }
    }
}

// ---------------------------------------------------------------------------
// K3: single-block scan: rowptr[d] = exclusive-sum over d of (sum_p bh[p][d])
// ---------------------------------------------------------------------------
__global__ __launch_bounds__(1024) void scan_kernel(
    const int* __restrict__ bh, int* __restrict__ rowptr, int N)
{
    __shared__ int tot[NMAX];
    __shared__ int csum[1024];
    const int tid = threadIdx.x;

    for (int d = tid; d < N; d += 1024) {
        int s = 0;
        #pragma unroll
        for (int p = 0; p < NP; ++p) s += bh[p * N + d];   // coalesced per pass
        tot[d] = s;
    }
    __syncthreads();

    const int CH = (N + 1023) / 1024;
    const int b = tid * CH;
    const int e = min(b + CH, N);
    int s = 0;
    for (int i = b; i < e; ++i) s += tot[i];
    csum[tid] = s;
    __syncthreads();
    for (int off = 1; off < 1024; off <<= 1) {
        int t = (tid >= off) ? csum[tid - off] : 0;
        __syncthreads();
        csum[tid] += t;
        __syncthreads();
    }
    int run = csum[tid] - s;
    for (int i = b; i < e; ++i) {
        rowptr[i] = run;
        run += tot[i];
    }
    if (tid == 1023) rowptr[N] = csum[1023];
}

// ---------------------------------------------------------------------------
// K4: scatter. Block p derives its own cursors: rowptr[d] + sum_{p'<p} bh[p'][d]
// (coalesced reads), then LDS-atomic rank + scattered ssrc write.
// ---------------------------------------------------------------------------
__global__ __launch_bounds__(256) void scatter_kernel(
    const int* __restrict__ src, const int* __restrict__ dst,
    const int* __restrict__ bh, const int* __restrict__ rowptr,
    int* __restrict__ ssrc, int N, int E, int C)
{
    __shared__ int cur[NMAX];
    const int p = blockIdx.x, tid = threadIdx.x;
    for (int d = tid; d < N; d += 256) {
        int c = rowptr[d];
        for (int q = 0; q < p; ++q) c += bh[q * N + d];    // independent, coalesced
        cur[d] = c;
    }
    __syncthreads();

    const int lo = p * C;
    const int hi = min(lo + C, E);
    const int n = hi - lo;
    if (n <= 0) return;

    if ((E & 3) == 0) {
        const int4* s4 = (const int4*)(src + lo);
        const int4* d4 = (const int4*)(dst + lo);
        const int n4 = n >> 2;
        for (int i = tid; i < n4; i += 256) {
            int4 s = s4[i];
            int4 d = d4[i];
            int p0 = atomicAdd(&cur[d.x], 1); ssrc[p0] = s.x;
            int p1 = atomicAdd(&cur[d.y], 1); ssrc[p1] = s.y;
            int p2 = atomicAdd(&cur[d.z], 1); ssrc[p2] = s.z;
            int p3 = atomicAdd(&cur[d.w], 1); ssrc[p3] = s.w;
        }
        for (int i = lo + (n4 << 2) + tid; i < hi; i += 256) {
            int pos = atomicAdd(&cur[dst[i]], 1); ssrc[pos] = src[i];
        }
    } else {
        for (int i = lo + tid; i < hi; i += 256) {
            int pos = atomicAdd(&cur[dst[i]], 1); ssrc[pos] = src[i];
        }
    }
}

// ---------------------------------------------------------------------------
// K5: half-wave-per-node softmax agg + residual + LayerNorm.
// bf16 K/V gathers, 4-edge batches, software-pipelined gather preload.
// ---------------------------------------------------------------------------
__global__ __launch_bounds__(256) void agg_kernel(
    const float* __restrict__ Qb, const unsigned short* __restrict__ KVu,
    const float* __restrict__ Rb,
    const int* __restrict__ rowptr, const int* __restrict__ ssrc,
    const float* __restrict__ gamma, const float* __restrict__ beta,
    float* __restrict__ out, int N)
{
    const int wave = threadIdx.x >> 6;
    const int lane = threadIdx.x & 63;
    const int half = lane >> 5;
    const int lh = lane & 31;
    const int n = blockIdx.x * 8 + wave * 2 + half;
    if (n >= N) return;
    const int d0 = lh * 4;

    const float4 q = *reinterpret_cast<const float4*>(&Qb[(size_t)n * 128 + d0]);
    const int beg = rowptr[n];
    const int end = rowptr[n + 1];

    float4 A0 = make_float4(0.f, 0.f, 0.f, 0.f), A1 = A0, A2 = A0, A3 = A0;
    float L0 = 0.f, L1 = 0.f, L2 = 0.f, L3 = 0.f;

#define BF4(U2, F4)                                                   \
    {                                                                 \
        F4.x = __uint_as_float((U2).x << 16);                         \
        F4.y = __uint_as_float((U2).x & 0xFFFF0000u);                 \
        F4.z = __uint_as_float((U2).y << 16);                         \
        F4.w = __uint_as_float((U2).y & 0xFFFF0000u);                 \
    }
#define STEP(KU, VU, A, L)                                            \
    {                                                                 \
        float4 kf, vf;                                                \
        BF4(KU, kf);                                                  \
        float p = q.x * kf.x + q.y * kf.y + q.z * kf.z + q.w * kf.w;  \
        p += __shfl_xor(p, 1);                                        \
        p += __shfl_xor(p, 2);                                        \
        p += __shfl_xor(p, 4);                                        \
        const float e1 = exp2f(p * SC2);                              \
        BF4(VU, vf);                                                  \
        A.x += e1 * vf.x;                                             \
        A.y += e1 * vf.y;                                             \
        A.z += e1 * vf.z;                                             \
        A.w += e1 * vf.w;                                             \
        L += e1;                                                      \
    }
#define LOADB(JJ)                                                     \
    {                                                                 \
        const int t0 = ssrc[JJ], t1 = ssrc[(JJ) + 1];                 \
        const int t2 = ssrc[(JJ) + 2], t3 = ssrc[(JJ) + 3];           \
        nk0 = *reinterpret_cast<const uint2*>(&KVu[(size_t)t0 * 256 + d0]);       \
        nv0 = *reinterpret_cast<const uint2*>(&KVu[(size_t)t0 * 256 + 128 + d0]); \
        nk1 = *reinterpret_cast<const uint2*>(&KVu[(size_t)t1 * 256 + d0]);       \
        nv1 = *reinterpret_cast<const uint2*>(&KVu[(size_t)t1 * 256 + 128 + d0]); \
        nk2 = *reinterpret_cast<const uint2*>(&KVu[(size_t)t2 * 256 + d0]);       \
        nv2 = *reinterpret_cast<const uint2*>(&KVu[(size_t)t2 * 256 + 128 + d0]); \
        nk3 = *reinterpret_cast<const uint2*>(&KVu[(size_t)t3 * 256 + d0]);       \
        nv3 = *reinterpret_cast<const uint2*>(&KVu[(size_t)t3 * 256 + 128 + d0]); \
    }

    uint2 nk0, nv0, nk1, nv1, nk2, nv2, nk3, nv3;
    int j = beg;
    const int nfull = (end - beg) >> 2;
    if (nfull > 0) {
        LOADB(beg);
        for (int bi = 1; bi < nfull; ++bi) {
            const uint2 ck0 = nk0, cv0 = nv0, ck1 = nk1, cv1 = nv1;
            const uint2 ck2 = nk2, cv2 = nv2, ck3 = nk3, cv3 = nv3;
            LOADB(beg + bi * 4);               // issue next gathers early
            STEP(ck0, cv0, A0, L0);
            STEP(ck1, cv1, A1, L1);
            STEP(ck2, cv2, A2, L2);
            STEP(ck3, cv3, A3, L3);
        }
        STEP(nk0, nv0, A0, L0);
        STEP(nk1, nv1, A1, L1);
        STEP(nk2, nv2, A2, L2);
        STEP(nk3, nv3, A3, L3);
        j = beg + nfull * 4;
    }
    for (; j < end; ++j) {
        const int s0 = ssrc[j];
        const uint2 k0 = *reinterpret_cast<const uint2*>(&KVu[(size_t)s0 * 256 + d0]);
        const uint2 v0 = *reinterpret_cast<const uint2*>(&KVu[(size_t)s0 * 256 + 128 + d0]);
        STEP(k0, v0, A0, L0);
    }
#undef LOADB
#undef STEP
#undef BF4

    const float L = (L0 + L1) + (L2 + L3);
    const float inv = 1.f / (L + 1e-12f);          // empty segment -> x = r
    const float4 r = *reinterpret_cast<const float4*>(&Rb[(size_t)n * 128 + d0]);
    float4 x;
    x.x = ((A0.x + A1.x) + (A2.x + A3.x)) * inv + r.x;
    x.y = ((A0.y + A1.y) + (A2.y + A3.y)) * inv + r.y;
    x.z = ((A0.z + A1.z) + (A2.z + A3.z)) * inv + r.z;
    x.w = ((A0.w + A1.w) + (A2.w + A3.w)) * inv + r.w;

    float s1v = x.x + x.y + x.z + x.w;
    float s2v = x.x * x.x + x.y * x.y + x.z * x.z + x.w * x.w;
    #pragma unroll
    for (int off = 16; off; off >>= 1) {
        s1v += __shfl_xor(s1v, off);
        s2v += __shfl_xor(s2v, off);
    }
    const float mu = s1v * (1.f / 128.f);
    float var = s2v * (1.f / 128.f) - mu * mu;
    var = fmaxf(var, 0.f);
    const float rs = rsqrtf(var + LN_EPS);

    const float4 g = *reinterpret_cast<const float4*>(&gamma[d0]);
    const float4 b = *reinterpret_cast<const float4*>(&beta[d0]);
    float4 o;
    o.x = g.x * (x.x - mu) * rs + b.x;
    o.y = g.y * (x.y - mu) * rs + b.y;
    o.z = g.z * (x.z - mu) * rs + b.z;
    o.w = g.w * (x.w - mu) * rs + b.w;
    *reinterpret_cast<float4*>(&out[(size_t)n * 128 + d0]) = o;
}

// ---------------------------------------------------------------------------
extern "C" void kernel_launch(void* const* d_in, const int* in_sizes, int n_in,
                              void* d_out, int out_size, void* d_ws, size_t ws_size,
                              hipStream_t stream)
{
    const float* nodes = (const float*)d_in[0];
    const float* W_Q   = (const float*)d_in[1];
    const float* W_K   = (const float*)d_in[2];
    const float* W_V   = (const float*)d_in[3];
    const float* W_res = (const float*)d_in[4];
    const float* b_res = (const float*)d_in[5];
    const float* gamma = (const float*)d_in[6];
    const float* beta  = (const float*)d_in[7];
    const int*   eidx  = (const int*)d_in[8];

    const int N = in_sizes[0] / FDIM;
    const int E = in_sizes[8] / 2;
    const int* src = eidx;
    const int* dst = eidx + E;

    float* out = (float*)d_out;

    // workspace carve
    unsigned short* KVu = (unsigned short*)d_ws;              // N*256 bf16
    float* Qb = (float*)(KVu + (size_t)N * 256);              // N*128 f32
    float* Rb = Qb + (size_t)N * 128;                         // N*128 f32
    int* bh     = (int*)(Rb + (size_t)N * 128);               // NP*N
    int* rowptr = bh + (size_t)NP * N;                        // N+1
    int* ssrc   = rowptr + (N + 1);                           // E

    const int C = (((E + NP - 1) / NP) + 3) & ~3;             // chunk, mult of 4
    const int nG = (N + 63) / 64;

    hist_kernel<<<NP, 256, 0, stream>>>(dst, bh, N, E, C);
    dim3 ggrid(nG, 4);
    gemm_kernel<<<ggrid, 256, 0, stream>>>(nodes, W_Q, W_K, W_V, W_res, b_res,
                                           Qb, KVu, Rb, N);
    scan_kernel<<<1, 1024, 0, stream>>>(bh, rowptr, N);
    scatter_kernel<<<NP, 256, 0, stream>>>(src, dst, bh, rowptr, ssrc, N, E, C);
    agg_kernel<<<(N + 7) / 8, 256, 0, stream>>>(Qb, KVu, Rb, rowptr, ssrc,
                                                gamma, beta, out, N);
}

// Round 8
// 158.388 us; speedup vs baseline: 2.2429x; 2.2429x over previous
//
#include <hip/hip_runtime.h>
#include <math.h>

#define FDIM 128
#define NP 32                 // CSR partition blocks
#define NMAX 10240            // LDS histogram capacity (N=10000)
static constexpr float SC2 = 0.17677669529663687f * 1.4426950408889634f; // (1/sqrt(32))*log2(e)
static constexpr float LN_EPS = 1e-5f;

__device__ __forceinline__ unsigned short f2bf(float f) {
    unsigned u = __float_as_uint(f);
    unsigned r = u + 0x7FFFu + ((u >> 16) & 1u);   // RNE
    return (unsigned short)(r >> 16);
}

// ---------------------------------------------------------------------------
// K1: fused 4-way GEMM (blockIdx.y 0..3) + LDS histogram (y==4, x<NP).
// GEMM: nodes[N,128] @ {W_Q,W_K,W_V,W_res}; Q,R fp32; K,V bf16 in KVu[n][256].
// Hist: bh[p*N+d] per-partition counts, LDS atomics only.
// ---------------------------------------------------------------------------
__global__ __launch_bounds__(256) void gemm_hist_kernel(
    const float* __restrict__ nodes,
    const float* __restrict__ Wq, const float* __restrict__ Wk,
    const float* __restrict__ Wv, const float* __restrict__ Wr,
    const float* __restrict__ br,
    float* __restrict__ Qb, unsigned short* __restrict__ KVu,
    float* __restrict__ Rb, int N,
    const int* __restrict__ dst, int* __restrict__ bh, int E, int C)
{
    __shared__ __align__(16) char smem[NMAX * 4];   // 40KB: union of h[] / As[]
    const int tid = threadIdx.x;
    const int wi = blockIdx.y;

    if (wi == 4) {                    // ---- histogram partition ----
        const int p = blockIdx.x;
        if (p >= NP) return;
        int* h = (int*)smem;
        for (int i = tid; i < N; i += 256) h[i] = 0;
        __syncthreads();
        const int lo = p * C;
        const int hi = min(lo + C, E);
        const int n = hi - lo;
        if (n > 0) {
            if (((lo | E) & 3) == 0) {
                const int4* d4 = (const int4*)(dst + lo);
                const int n4 = n >> 2;
                for (int i = tid; i < n4; i += 256) {
                    int4 d = d4[i];
                    atomicAdd(&h[d.x], 1); atomicAdd(&h[d.y], 1);
                    atomicAdd(&h[d.z], 1); atomicAdd(&h[d.w], 1);
                }
                for (int i = lo + (n4 << 2) + tid; i < hi; i += 256)
                    atomicAdd(&h[dst[i]], 1);
            } else {
                for (int i = lo + tid; i < hi; i += 256)
                    atomicAdd(&h[dst[i]], 1);
            }
        }
        __syncthreads();
        for (int i = tid; i < N; i += 256) bh[p * N + i] = h[i];
        return;
    }

    // ---- GEMM partition ----
    float (*As)[FDIM] = (float(*)[FDIM])smem;       // 32KB of the 40KB
    const int row0 = blockIdx.x * 64;
    const float* __restrict__ W = (wi == 0) ? Wq : (wi == 1) ? Wk : (wi == 2) ? Wv : Wr;

    #pragma unroll
    for (int i = 0; i < 8; ++i) {
        int idx = tid + i * 256;          // 0..2047 float4s
        int r = idx >> 5, c4 = idx & 31;
        int gr = row0 + r;
        float4 v = make_float4(0.f, 0.f, 0.f, 0.f);
        if (gr < N) v = *reinterpret_cast<const float4*>(&nodes[(size_t)gr * FDIM + c4 * 4]);
        *reinterpret_cast<float4*>(&As[r][c4 * 4]) = v;
    }
    __syncthreads();

    const int cg = tid & 31;
    const int rg = tid >> 5;
    const int c0 = cg * 4;
    const int r0 = rg * 8;

    float acc[8][4];
    #pragma unroll
    for (int i = 0; i < 8; ++i)
        #pragma unroll
        for (int j = 0; j < 4; ++j) acc[i][j] = 0.f;

    #pragma unroll 2
    for (int k = 0; k < FDIM; k += 2) {
        const float4 wA = *reinterpret_cast<const float4*>(&W[k * FDIM + c0]);
        const float4 wB = *reinterpret_cast<const float4*>(&W[(k + 1) * FDIM + c0]);
        float2 a[8];
        #pragma unroll
        for (int i = 0; i < 8; ++i)
            a[i] = *reinterpret_cast<const float2*>(&As[r0 + i][k]);
        #pragma unroll
        for (int i = 0; i < 8; ++i) {
            acc[i][0] += a[i].x * wA.x + a[i].y * wB.x;
            acc[i][1] += a[i].x * wA.y + a[i].y * wB.y;
            acc[i][2] += a[i].x * wA.z + a[i].y * wB.z;
            acc[i][3] += a[i].x * wA.w + a[i].y * wB.w;
        }
    }

    float4 bias = make_float4(0.f, 0.f, 0.f, 0.f);
    if (wi == 3) bias = *reinterpret_cast<const float4*>(&br[c0]);

    #pragma unroll
    for (int i = 0; i < 8; ++i) {
        int gr = row0 + r0 + i;
        if (gr >= N) continue;
        if (wi == 0 || wi == 3) {
            float4 o = make_float4(acc[i][0] + bias.x, acc[i][1] + bias.y,
                                   acc[i][2] + bias.z, acc[i][3] + bias.w);
            float* dp = (wi == 0) ? &Qb[(size_t)gr * 128 + c0] : &Rb[(size_t)gr * 128 + c0];
            *reinterpret_cast<float4*>(dp) = o;
        } else {
            ushort4 o;
            o.x = f2bf(acc[i][0]); o.y = f2bf(acc[i][1]);
            o.z = f2bf(acc[i][2]); o.w = f2bf(acc[i][3]);
            unsigned short* dp = &KVu[(size_t)gr * 256 + ((wi == 2) ? 128 : 0) + c0];
            *reinterpret_cast<ushort4*>(dp) = o;
        }
    }
}

// ---------------------------------------------------------------------------
// K2: single-block scan. Produces rowptr[0..N] and converts bh IN-PLACE from
// per-partition counts to per-partition exclusive bases:
//   bh[p*N+d] <- rowptr[d] + sum_{p'<p} count[p'][d]
// ---------------------------------------------------------------------------
__global__ __launch_bounds__(1024) void scan_kernel(
    int* __restrict__ bh, int* __restrict__ rowptr, int N)
{
    __shared__ int tot[NMAX];
    __shared__ int csum[1024];
    const int tid = threadIdx.x;

    // per-node degree
    for (int d = tid; d < N; d += 1024) {
        int s = 0;
        #pragma unroll
        for (int p = 0; p < NP; ++p) s += bh[p * N + d];
        tot[d] = s;
    }
    __syncthreads();

    // chunked exclusive scan over d
    const int CH = (N + 1023) / 1024;
    const int b = tid * CH;
    const int e = min(b + CH, N);
    int s = 0;
    for (int i = b; i < e; ++i) s += tot[i];
    csum[tid] = s;
    __syncthreads();
    for (int off = 1; off < 1024; off <<= 1) {
        int t = (tid >= off) ? csum[tid - off] : 0;
        __syncthreads();
        csum[tid] += t;
        __syncthreads();
    }
    int run = csum[tid] - s;                 // exclusive base of this chunk
    for (int i = b; i < e; ++i) {
        const int t = tot[i];                // save BEFORE clobber
        rowptr[i] = run;
        tot[i] = run;                        // stash node base for phase 2
        run += t;
    }
    if (tid == 1023) rowptr[N] = csum[1023];
    __syncthreads();

    // convert bh counts -> partition bases (in place)
    for (int d = tid; d < N; d += 1024) {
        int c = tot[d];
        #pragma unroll
        for (int p = 0; p < NP; ++p) {
            const int cnt = bh[p * N + d];
            bh[p * N + d] = c;
            c += cnt;
        }
    }
}

// ---------------------------------------------------------------------------
// K3: scatter src ids into CSR slots. Cursors from bh-bases (coalesced),
// LDS atomics for rank.
// ---------------------------------------------------------------------------
__global__ __launch_bounds__(256) void scatter_kernel(
    const int* __restrict__ src, const int* __restrict__ dst,
    const int* __restrict__ base, int* __restrict__ ssrc,
    int N, int E, int C)
{
    __shared__ int cur[NMAX];
    const int p = blockIdx.x, tid = threadIdx.x;
    for (int d = tid; d < N; d += 256) cur[d] = base[p * N + d];
    __syncthreads();

    const int lo = p * C;
    const int hi = min(lo + C, E);
    const int n = hi - lo;
    if (n <= 0) return;

    if (((lo | E) & 3) == 0) {
        const int4* s4 = (const int4*)(src + lo);
        const int4* d4 = (const int4*)(dst + lo);
        const int n4 = n >> 2;
        for (int i = tid; i < n4; i += 256) {
            int4 s = s4[i];
            int4 d = d4[i];
            int p0 = atomicAdd(&cur[d.x], 1); ssrc[p0] = s.x;
            int p1 = atomicAdd(&cur[d.y], 1); ssrc[p1] = s.y;
            int p2 = atomicAdd(&cur[d.z], 1); ssrc[p2] = s.z;
            int p3 = atomicAdd(&cur[d.w], 1); ssrc[p3] = s.w;
        }
        for (int i = lo + (n4 << 2) + tid; i < hi; i += 256) {
            int pos = atomicAdd(&cur[dst[i]], 1); ssrc[pos] = src[i];
        }
    } else {
        for (int i = lo + tid; i < hi; i += 256) {
            int pos = atomicAdd(&cur[dst[i]], 1); ssrc[pos] = src[i];
        }
    }
}

// ---------------------------------------------------------------------------
// K4: half-wave-per-node softmax agg + residual + LayerNorm.
// bf16 K/V gathers, 4-edge batches, software-pipelined gather preload.
// ---------------------------------------------------------------------------
__global__ __launch_bounds__(256) void agg_kernel(
    const float* __restrict__ Qb, const unsigned short* __restrict__ KVu,
    const float* __restrict__ Rb,
    const int* __restrict__ rowptr, const int* __restrict__ ssrc,
    const float* __restrict__ gamma, const float* __restrict__ beta,
    float* __restrict__ out, int N)
{
    const int wave = threadIdx.x >> 6;
    const int lane = threadIdx.x & 63;
    const int half = lane >> 5;
    const int lh = lane & 31;
    const int n = blockIdx.x * 8 + wave * 2 + half;
    if (n >= N) return;
    const int d0 = lh * 4;

    const float4 q = *reinterpret_cast<const float4*>(&Qb[(size_t)n * 128 + d0]);
    const int beg = rowptr[n];
    const int end = rowptr[n + 1];

    float4 A0 = make_float4(0.f, 0.f, 0.f, 0.f), A1 = A0, A2 = A0, A3 = A0;
    float L0 = 0.f, L1 = 0.f, L2 = 0.f, L3 = 0.f;

#define BF4(U2, F4)                                                   \
    {                                                                 \
        F4.x = __uint_as_float((U2).x << 16);                         \
        F4.y = __uint_as_float((U2).x & 0xFFFF0000u);                 \
        F4.z = __uint_as_float((U2).y << 16);                         \
        F4.w = __uint_as_float((U2).y & 0xFFFF0000u);                 \
    }
#define STEP(KU, VU, A, L)                                            \
    {                                                                 \
        float4 kf, vf;                                                \
        BF4(KU, kf);                                                  \
        float p = q.x * kf.x + q.y * kf.y + q.z * kf.z + q.w * kf.w;  \
        p += __shfl_xor(p, 1);                                        \
        p += __shfl_xor(p, 2);                                        \
        p += __shfl_xor(p, 4);                                        \
        const float e1 = exp2f(p * SC2);                              \
        BF4(VU, vf);                                                  \
        A.x += e1 * vf.x;                                             \
        A.y += e1 * vf.y;                                             \
        A.z += e1 * vf.z;                                             \
        A.w += e1 * vf.w;                                             \
        L += e1;                                                      \
    }
#define LOADB(JJ)                                                     \
    {                                                                 \
        const int t0 = ssrc[JJ], t1 = ssrc[(JJ) + 1];                 \
        const int t2 = ssrc[(JJ) + 2], t3 = ssrc[(JJ) + 3];           \
        nk0 = *reinterpret_cast<const uint2*>(&KVu[(size_t)t0 * 256 + d0]);       \
        nv0 = *reinterpret_cast<const uint2*>(&KVu[(size_t)t0 * 256 + 128 + d0]); \
        nk1 = *reinterpret_cast<const uint2*>(&KVu[(size_t)t1 * 256 + d0]);       \
        nv1 = *reinterpret_cast<const uint2*>(&KVu[(size_t)t1 * 256 + 128 + d0]); \
        nk2 = *reinterpret_cast<const uint2*>(&KVu[(size_t)t2 * 256 + d0]);       \
        nv2 = *reinterpret_cast<const uint2*>(&KVu[(size_t)t2 * 256 + 128 + d0]); \
        nk3 = *reinterpret_cast<const uint2*>(&KVu[(size_t)t3 * 256 + d0]);       \
        nv3 = *reinterpret_cast<const uint2*>(&KVu[(size_t)t3 * 256 + 128 + d0]); \
    }

    uint2 nk0, nv0, nk1, nv1, nk2, nv2, nk3, nv3;
    int j = beg;
    const int nfull = (end - beg) >> 2;
    if (nfull > 0) {
        LOADB(beg);
        for (int bi = 1; bi < nfull; ++bi) {
            const uint2 ck0 = nk0, cv0 = nv0, ck1 = nk1, cv1 = nv1;
            const uint2 ck2 = nk2, cv2 = nv2, ck3 = nk3, cv3 = nv3;
            LOADB(beg + bi * 4);               // issue next gathers early
            STEP(ck0, cv0, A0, L0);
            STEP(ck1, cv1, A1, L1);
            STEP(ck2, cv2, A2, L2);
            STEP(ck3, cv3, A3, L3);
        }
        STEP(nk0, nv0, A0, L0);
        STEP(nk1, nv1, A1, L1);
        STEP(nk2, nv2, A2, L2);
        STEP(nk3, nv3, A3, L3);
        j = beg + nfull * 4;
    }
    for (; j < end; ++j) {
        const int s0 = ssrc[j];
        const uint2 k0 = *reinterpret_cast<const uint2*>(&KVu[(size_t)s0 * 256 + d0]);
        const uint2 v0 = *reinterpret_cast<const uint2*>(&KVu[(size_t)s0 * 256 + 128 + d0]);
        STEP(k0, v0, A0, L0);
    }
#undef LOADB
#undef STEP
#undef BF4

    const float L = (L0 + L1) + (L2 + L3);
    const float inv = 1.f / (L + 1e-12f);          // empty segment -> x = r
    const float4 r = *reinterpret_cast<const float4*>(&Rb[(size_t)n * 128 + d0]);
    float4 x;
    x.x = ((A0.x + A1.x) + (A2.x + A3.x)) * inv + r.x;
    x.y = ((A0.y + A1.y) + (A2.y + A3.y)) * inv + r.y;
    x.z = ((A0.z + A1.z) + (A2.z + A3.z)) * inv + r.z;
    x.w = ((A0.w + A1.w) + (A2.w + A3.w)) * inv + r.w;

    float s1v = x.x + x.y + x.z + x.w;
    float s2v = x.x * x.x + x.y * x.y + x.z * x.z + x.w * x.w;
    #pragma unroll
    for (int off = 16; off; off >>= 1) {
        s1v += __shfl_xor(s1v, off);
        s2v += __shfl_xor(s2v, off);
    }
    const float mu = s1v * (1.f / 128.f);
    float var = s2v * (1.f / 128.f) - mu * mu;
    var = fmaxf(var, 0.f);
    const float rs = rsqrtf(var + LN_EPS);

    const float4 g = *reinterpret_cast<const float4*>(&gamma[d0]);
    const float4 b = *reinterpret_cast<const float4*>(&beta[d0]);
    float4 o;
    o.x = g.x * (x.x - mu) * rs + b.x;
    o.y = g.y * (x.y - mu) * rs + b.y;
    o.z = g.z * (x.z - mu) * rs + b.z;
    o.w = g.w * (x.w - mu) * rs + b.w;
    *reinterpret_cast<float4*>(&out[(size_t)n * 128 + d0]) = o;
}

// ---------------------------------------------------------------------------
extern "C" void kernel_launch(void* const* d_in, const int* in_sizes, int n_in,
                              void* d_out, int out_size, void* d_ws, size_t ws_size,
                              hipStream_t stream)
{
    const float* nodes = (const float*)d_in[0];
    const float* W_Q   = (const float*)d_in[1];
    const float* W_K   = (const float*)d_in[2];
    const float* W_V   = (const float*)d_in[3];
    const float* W_res = (const float*)d_in[4];
    const float* b_res = (const float*)d_in[5];
    const float* gamma = (const float*)d_in[6];
    const float* beta  = (const float*)d_in[7];
    const int*   eidx  = (const int*)d_in[8];

    const int N = in_sizes[0] / FDIM;
    const int E = in_sizes[8] / 2;
    const int* src = eidx;
    const int* dst = eidx + E;

    float* out = (float*)d_out;

    // workspace carve (same footprint as R5)
    unsigned short* KVu = (unsigned short*)d_ws;              // N*256 bf16
    float* Qb = (float*)(KVu + (size_t)N * 256);              // N*128 f32
    float* Rb = Qb + (size_t)N * 128;                         // N*128 f32
    int* bh     = (int*)(Rb + (size_t)N * 128);               // NP*N (counts -> bases)
    int* rowptr = bh + (size_t)NP * N;                        // N+1
    int* ssrc   = rowptr + (N + 1);                           // E

    const int C = (((E + NP - 1) / NP) + 3) & ~3;             // chunk, mult of 4
    const int nG = (N + 63) / 64;

    dim3 ggrid(nG, 5);                                        // y==4 -> histogram
    gemm_hist_kernel<<<ggrid, 256, 0, stream>>>(nodes, W_Q, W_K, W_V, W_res, b_res,
                                                Qb, KVu, Rb, N, dst, bh, E, C);
    scan_kernel<<<1, 1024, 0, stream>>>(bh, rowptr, N);
    scatter_kernel<<<NP, 256, 0, stream>>>(src, dst, bh, ssrc, N, E, C);
    agg_kernel<<<(N + 7) / 8, 256, 0, stream>>>(Qb, KVu, Rb, rowptr, ssrc,
                                                gamma, beta, out, N);
}

// Round 9
// 116.694 us; speedup vs baseline: 3.0443x; 1.3573x over previous
//
#include <hip/hip_runtime.h>
#include <math.h>

#define FDIM 128
#define NP 32                 // CSR partition blocks
#define NMAX 10240            // LDS capacity (N=10000)
static constexpr float SC2 = 0.17677669529663687f * 1.4426950408889634f; // (1/sqrt(32))*log2(e)
static constexpr float LN_EPS = 1e-5f;

__device__ __forceinline__ unsigned short f2bf(float f) {
    unsigned u = __float_as_uint(f);
    unsigned r = u + 0x7FFFu + ((u >> 16) & 1u);   // RNE
    return (unsigned short)(r >> 16);
}

// ---------------------------------------------------------------------------
// K1: fused 4-way GEMM (blockIdx.y 0..3) + LDS histogram (y==4, x<NP).
// ---------------------------------------------------------------------------
__global__ __launch_bounds__(256) void gemm_hist_kernel(
    const float* __restrict__ nodes,
    const float* __restrict__ Wq, const float* __restrict__ Wk,
    const float* __restrict__ Wv, const float* __restrict__ Wr,
    const float* __restrict__ br,
    float* __restrict__ Qb, unsigned short* __restrict__ KVu,
    float* __restrict__ Rb, int N,
    const int* __restrict__ dst, int* __restrict__ bh, int E, int C)
{
    __shared__ __align__(16) char smem[NMAX * 4];   // 40KB: union of h[] / As[]
    const int tid = threadIdx.x;
    const int wi = blockIdx.y;

    if (wi == 4) {                    // ---- histogram partition ----
        const int p = blockIdx.x;
        if (p >= NP) return;
        int* h = (int*)smem;
        for (int i = tid; i < N; i += 256) h[i] = 0;
        __syncthreads();
        const int lo = p * C;
        const int hi = min(lo + C, E);
        const int n = hi - lo;
        if (n > 0) {
            if (((lo | E) & 3) == 0) {
                const int4* d4 = (const int4*)(dst + lo);
                const int n4 = n >> 2;
                for (int i = tid; i < n4; i += 256) {
                    int4 d = d4[i];
                    atomicAdd(&h[d.x], 1); atomicAdd(&h[d.y], 1);
                    atomicAdd(&h[d.z], 1); atomicAdd(&h[d.w], 1);
                }
                for (int i = lo + (n4 << 2) + tid; i < hi; i += 256)
                    atomicAdd(&h[dst[i]], 1);
            } else {
                for (int i = lo + tid; i < hi; i += 256)
                    atomicAdd(&h[dst[i]], 1);
            }
        }
        __syncthreads();
        for (int i = tid; i < N; i += 256) bh[p * N + i] = h[i];
        return;
    }

    // ---- GEMM partition ----
    float (*As)[FDIM] = (float(*)[FDIM])smem;       // 32KB of the 40KB
    const int row0 = blockIdx.x * 64;
    const float* __restrict__ W = (wi == 0) ? Wq : (wi == 1) ? Wk : (wi == 2) ? Wv : Wr;

    #pragma unroll
    for (int i = 0; i < 8; ++i) {
        int idx = tid + i * 256;          // 0..2047 float4s
        int r = idx >> 5, c4 = idx & 31;
        int gr = row0 + r;
        float4 v = make_float4(0.f, 0.f, 0.f, 0.f);
        if (gr < N) v = *reinterpret_cast<const float4*>(&nodes[(size_t)gr * FDIM + c4 * 4]);
        *reinterpret_cast<float4*>(&As[r][c4 * 4]) = v;
    }
    __syncthreads();

    const int cg = tid & 31;
    const int rg = tid >> 5;
    const int c0 = cg * 4;
    const int r0 = rg * 8;

    float acc[8][4];
    #pragma unroll
    for (int i = 0; i < 8; ++i)
        #pragma unroll
        for (int j = 0; j < 4; ++j) acc[i][j] = 0.f;

    #pragma unroll 2
    for (int k = 0; k < FDIM; k += 2) {
        const float4 wA = *reinterpret_cast<const float4*>(&W[k * FDIM + c0]);
        const float4 wB = *reinterpret_cast<const float4*>(&W[(k + 1) * FDIM + c0]);
        float2 a[8];
        #pragma unroll
        for (int i = 0; i < 8; ++i)
            a[i] = *reinterpret_cast<const float2*>(&As[r0 + i][k]);
        #pragma unroll
        for (int i = 0; i < 8; ++i) {
            acc[i][0] += a[i].x * wA.x + a[i].y * wB.x;
            acc[i][1] += a[i].x * wA.y + a[i].y * wB.y;
            acc[i][2] += a[i].x * wA.z + a[i].y * wB.z;
            acc[i][3] += a[i].x * wA.w + a[i].y * wB.w;
        }
    }

    float4 bias = make_float4(0.f, 0.f, 0.f, 0.f);
    if (wi == 3) bias = *reinterpret_cast<const float4*>(&br[c0]);

    #pragma unroll
    for (int i = 0; i < 8; ++i) {
        int gr = row0 + r0 + i;
        if (gr >= N) continue;
        if (wi == 0 || wi == 3) {
            float4 o = make_float4(acc[i][0] + bias.x, acc[i][1] + bias.y,
                                   acc[i][2] + bias.z, acc[i][3] + bias.w);
            float* dp = (wi == 0) ? &Qb[(size_t)gr * 128 + c0] : &Rb[(size_t)gr * 128 + c0];
            *reinterpret_cast<float4*>(dp) = o;
        } else {
            ushort4 o;
            o.x = f2bf(acc[i][0]); o.y = f2bf(acc[i][1]);
            o.z = f2bf(acc[i][2]); o.w = f2bf(acc[i][3]);
            unsigned short* dp = &KVu[(size_t)gr * 256 + ((wi == 2) ? 128 : 0) + c0];
            *reinterpret_cast<ushort4*>(dp) = o;
        }
    }
}

// ---------------------------------------------------------------------------
// K2a: deg[d] = sum_p bh[p][d]  (parallel across N)
// ---------------------------------------------------------------------------
__global__ __launch_bounds__(256) void deg_kernel(
    const int* __restrict__ bh, int* __restrict__ deg, int N)
{
    const int d = blockIdx.x * 256 + threadIdx.x;
    if (d < N) {
        int s = 0;
        #pragma unroll
        for (int p = 0; p < NP; ++p) s += bh[p * N + d];
        deg[d] = s;
    }
}

// ---------------------------------------------------------------------------
// K2b: single-block exclusive scan of deg -> rowptr  (only 40KB in, 40KB out)
// ---------------------------------------------------------------------------
__global__ __launch_bounds__(1024) void scan_kernel(
    const int* __restrict__ deg, int* __restrict__ rowptr, int N)
{
    __shared__ int tot[NMAX];
    __shared__ int csum[1024];
    const int tid = threadIdx.x;

    for (int d = tid; d < N; d += 1024) tot[d] = deg[d];
    __syncthreads();

    const int CH = (N + 1023) / 1024;
    const int b = tid * CH;
    const int e = min(b + CH, N);
    int s = 0;
    for (int i = b; i < e; ++i) s += tot[i];
    csum[tid] = s;
    __syncthreads();
    for (int off = 1; off < 1024; off <<= 1) {
        int t = (tid >= off) ? csum[tid - off] : 0;
        __syncthreads();
        csum[tid] += t;
        __syncthreads();
    }
    int run = csum[tid] - s;
    for (int i = b; i < e; ++i) {
        const int t = tot[i];
        rowptr[i] = run;
        run += t;
    }
    if (tid == 1023) rowptr[N] = csum[1023];
}

// ---------------------------------------------------------------------------
// K2c: convert bh counts -> per-partition exclusive bases, in place.
// bh[p][d] <- rowptr[d] + sum_{p'<p} count[p'][d]
// ---------------------------------------------------------------------------
__global__ __launch_bounds__(256) void base_kernel(
    int* __restrict__ bh, const int* __restrict__ rowptr, int N)
{
    const int d = blockIdx.x * 256 + threadIdx.x;
    if (d < N) {
        int c = rowptr[d];
        #pragma unroll
        for (int p = 0; p < NP; ++p) {
            const int cnt = bh[p * N + d];
            bh[p * N + d] = c;
            c += cnt;
        }
    }
}

// ---------------------------------------------------------------------------
// K3: scatter src ids into CSR slots. Cursors from bh-bases (coalesced),
// LDS atomics for rank.
// ---------------------------------------------------------------------------
__global__ __launch_bounds__(256) void scatter_kernel(
    const int* __restrict__ src, const int* __restrict__ dst,
    const int* __restrict__ base, int* __restrict__ ssrc,
    int N, int E, int C)
{
    __shared__ int cur[NMAX];
    const int p = blockIdx.x, tid = threadIdx.x;
    for (int d = tid; d < N; d += 256) cur[d] = base[p * N + d];
    __syncthreads();

    const int lo = p * C;
    const int hi = min(lo + C, E);
    const int n = hi - lo;
    if (n <= 0) return;

    if (((lo | E) & 3) == 0) {
        const int4* s4 = (const int4*)(src + lo);
        const int4* d4 = (const int4*)(dst + lo);
        const int n4 = n >> 2;
        for (int i = tid; i < n4; i += 256) {
            int4 s = s4[i];
            int4 d = d4[i];
            int p0 = atomicAdd(&cur[d.x], 1); ssrc[p0] = s.x;
            int p1 = atomicAdd(&cur[d.y], 1); ssrc[p1] = s.y;
            int p2 = atomicAdd(&cur[d.z], 1); ssrc[p2] = s.z;
            int p3 = atomicAdd(&cur[d.w], 1); ssrc[p3] = s.w;
        }
        for (int i = lo + (n4 << 2) + tid; i < hi; i += 256) {
            int pos = atomicAdd(&cur[dst[i]], 1); ssrc[pos] = src[i];
        }
    } else {
        for (int i = lo + tid; i < hi; i += 256) {
            int pos = atomicAdd(&cur[dst[i]], 1); ssrc[pos] = src[i];
        }
    }
}

// ---------------------------------------------------------------------------
// K4: half-wave-per-node softmax agg + residual + LayerNorm.
// bf16 K/V gathers, 4-edge batches, software-pipelined gather preload.
// ---------------------------------------------------------------------------
__global__ __launch_bounds__(256) void agg_kernel(
    const float* __restrict__ Qb, const unsigned short* __restrict__ KVu,
    const float* __restrict__ Rb,
    const int* __restrict__ rowptr, const int* __restrict__ ssrc,
    const float* __restrict__ gamma, const float* __restrict__ beta,
    float* __restrict__ out, int N)
{
    const int wave = threadIdx.x >> 6;
    const int lane = threadIdx.x & 63;
    const int half = lane >> 5;
    const int lh = lane & 31;
    const int n = blockIdx.x * 8 + wave * 2 + half;
    if (n >= N) return;
    const int d0 = lh * 4;

    const float4 q = *reinterpret_cast<const float4*>(&Qb[(size_t)n * 128 + d0]);
    const int beg = rowptr[n];
    const int end = rowptr[n + 1];

    float4 A0 = make_float4(0.f, 0.f, 0.f, 0.f), A1 = A0, A2 = A0, A3 = A0;
    float L0 = 0.f, L1 = 0.f, L2 = 0.f, L3 = 0.f;

#define BF4(U2, F4)                                                   \
    {                                                                 \
        F4.x = __uint_as_float((U2).x << 16);                         \
        F4.y = __uint_as_float((U2).x & 0xFFFF0000u);                 \
        F4.z = __uint_as_float((U2).y << 16);                         \
        F4.w = __uint_as_float((U2).y & 0xFFFF0000u);                 \
    }
#define STEP(KU, VU, A, L)                                            \
    {                                                                 \
        float4 kf, vf;                                                \
        BF4(KU, kf);                                                  \
        float p = q.x * kf.x + q.y * kf.y + q.z * kf.z + q.w * kf.w;  \
        p += __shfl_xor(p, 1);                                        \
        p += __shfl_xor(p, 2);                                        \
        p += __shfl_xor(p, 4);                                        \
        const float e1 = exp2f(p * SC2);                              \
        BF4(VU, vf);                                                  \
        A.x += e1 * vf.x;                                             \
        A.y += e1 * vf.y;                                             \
        A.z += e1 * vf.z;                                             \
        A.w += e1 * vf.w;                                             \
        L += e1;                                                      \
    }
#define LOADB(JJ)                                                     \
    {                                                                 \
        const int t0 = ssrc[JJ], t1 = ssrc[(JJ) + 1];                 \
        const int t2 = ssrc[(JJ) + 2], t3 = ssrc[(JJ) + 3];           \
        nk0 = *reinterpret_cast<const uint2*>(&KVu[(size_t)t0 * 256 + d0]);       \
        nv0 = *reinterpret_cast<const uint2*>(&KVu[(size_t)t0 * 256 + 128 + d0]); \
        nk1 = *reinterpret_cast<const uint2*>(&KVu[(size_t)t1 * 256 + d0]);       \
        nv1 = *reinterpret_cast<const uint2*>(&KVu[(size_t)t1 * 256 + 128 + d0]); \
        nk2 = *reinterpret_cast<const uint2*>(&KVu[(size_t)t2 * 256 + d0]);       \
        nv2 = *reinterpret_cast<const uint2*>(&KVu[(size_t)t2 * 256 + 128 + d0]); \
        nk3 = *reinterpret_cast<const uint2*>(&KVu[(size_t)t3 * 256 + d0]);       \
        nv3 = *reinterpret_cast<const uint2*>(&KVu[(size_t)t3 * 256 + 128 + d0]); \
    }

    uint2 nk0, nv0, nk1, nv1, nk2, nv2, nk3, nv3;
    int j = beg;
    const int nfull = (end - beg) >> 2;
    if (nfull > 0) {
        LOADB(beg);
        for (int bi = 1; bi < nfull; ++bi) {
            const uint2 ck0 = nk0, cv0 = nv0, ck1 = nk1, cv1 = nv1;
            const uint2 ck2 = nk2, cv2 = nv2, ck3 = nk3, cv3 = nv3;
            LOADB(beg + bi * 4);               // issue next gathers early
            STEP(ck0, cv0, A0, L0);
            STEP(ck1, cv1, A1, L1);
            STEP(ck2, cv2, A2, L2);
            STEP(ck3, cv3, A3, L3);
        }
        STEP(nk0, nv0, A0, L0);
        STEP(nk1, nv1, A1, L1);
        STEP(nk2, nv2, A2, L2);
        STEP(nk3, nv3, A3, L3);
        j = beg + nfull * 4;
    }
    for (; j < end; ++j) {
        const int s0 = ssrc[j];
        const uint2 k0 = *reinterpret_cast<const uint2*>(&KVu[(size_t)s0 * 256 + d0]);
        const uint2 v0 = *reinterpret_cast<const uint2*>(&KVu[(size_t)s0 * 256 + 128 + d0]);
        STEP(k0, v0, A0, L0);
    }
#undef LOADB
#undef STEP
#undef BF4

    const float L = (L0 + L1) + (L2 + L3);
    const float inv = 1.f / (L + 1e-12f);          // empty segment -> x = r
    const float4 r = *reinterpret_cast<const float4*>(&Rb[(size_t)n * 128 + d0]);
    float4 x;
    x.x = ((A0.x + A1.x) + (A2.x + A3.x)) * inv + r.x;
    x.y = ((A0.y + A1.y) + (A2.y + A3.y)) * inv + r.y;
    x.z = ((A0.z + A1.z) + (A2.z + A3.z)) * inv + r.z;
    x.w = ((A0.w + A1.w) + (A2.w + A3.w)) * inv + r.w;

    float s1v = x.x + x.y + x.z + x.w;
    float s2v = x.x * x.x + x.y * x.y + x.z * x.z + x.w * x.w;
    #pragma unroll
    for (int off = 16; off; off >>= 1) {
        s1v += __shfl_xor(s1v, off);
        s2v += __shfl_xor(s2v, off);
    }
    const float mu = s1v * (1.f / 128.f);
    float var = s2v * (1.f / 128.f) - mu * mu;
    var = fmaxf(var, 0.f);
    const float rs = rsqrtf(var + LN_EPS);

    const float4 g = *reinterpret_cast<const float4*>(&gamma[d0]);
    const float4 b = *reinterpret_cast<const float4*>(&beta[d0]);
    float4 o;
    o.x = g.x * (x.x - mu) * rs + b.x;
    o.y = g.y * (x.y - mu) * rs + b.y;
    o.z = g.z * (x.z - mu) * rs + b.z;
    o.w = g.w * (x.w - mu) * rs + b.w;
    *reinterpret_cast<float4*>(&out[(size_t)n * 128 + d0]) = o;
}

// ---------------------------------------------------------------------------
extern "C" void kernel_launch(void* const* d_in, const int* in_sizes, int n_in,
                              void* d_out, int out_size, void* d_ws, size_t ws_size,
                              hipStream_t stream)
{
    const float* nodes = (const float*)d_in[0];
    const float* W_Q   = (const float*)d_in[1];
    const float* W_K   = (const float*)d_in[2];
    const float* W_V   = (const float*)d_in[3];
    const float* W_res = (const float*)d_in[4];
    const float* b_res = (const float*)d_in[5];
    const float* gamma = (const float*)d_in[6];
    const float* beta  = (const float*)d_in[7];
    const int*   eidx  = (const int*)d_in[8];

    const int N = in_sizes[0] / FDIM;
    const int E = in_sizes[8] / 2;
    const int* src = eidx;
    const int* dst = eidx + E;

    float* out = (float*)d_out;

    // workspace carve
    unsigned short* KVu = (unsigned short*)d_ws;              // N*256 bf16
    float* Qb = (float*)(KVu + (size_t)N * 256);              // N*128 f32
    float* Rb = Qb + (size_t)N * 128;                         // N*128 f32
    int* bh     = (int*)(Rb + (size_t)N * 128);               // NP*N (counts -> bases)
    int* rowptr = bh + (size_t)NP * N;                        // N+1
    int* deg    = rowptr + (N + 1);                           // N
    int* ssrc   = deg + N;                                    // E

    const int C = (((E + NP - 1) / NP) + 3) & ~3;             // chunk, mult of 4
    const int nG = (N + 63) / 64;
    const int nB = (N + 255) / 256;

    dim3 ggrid(nG, 5);                                        // y==4 -> histogram
    gemm_hist_kernel<<<ggrid, 256, 0, stream>>>(nodes, W_Q, W_K, W_V, W_res, b_res,
                                                Qb, KVu, Rb, N, dst, bh, E, C);
    deg_kernel<<<nB, 256, 0, stream>>>(bh, deg, N);
    scan_kernel<<<1, 1024, 0, stream>>>(deg, rowptr, N);
    base_kernel<<<nB, 256, 0, stream>>>(bh, rowptr, N);
    scatter_kernel<<<NP, 256, 0, stream>>>(src, dst, bh, ssrc, N, E, C);
    agg_kernel<<<(N + 7) / 8, 256, 0, stream>>>(Qb, KVu, Rb, rowptr, ssrc,
                                                gamma, beta, out, N);
}